// Round 1
// baseline (1654.543 us; speedup 1.0000x reference)
//
#include <hip/hip_runtime.h>

// Implicit-GEMM formulation of the masked split-context/center 3x3 conv.
// M = 8*256*256 rows (b,h,w), N = 256 output features, K = 9 taps * 128 ch.
// Tap t != 4: context channels [0,128) with kernel[ky][kx][g=0].
// Tap t == 4: center channels [128,256) with kernel[1][1][g=1] (the mask).
// bf16 MFMA 16x16x32; fp32 accumulate; threshold 0.1925 >> expected ~0.04.

typedef __attribute__((ext_vector_type(8))) short bf16x8;   // 8 bf16 = 4 VGPRs
typedef __attribute__((ext_vector_type(4))) float f32x4;

#define BM 128
#define BN 128
#define BK 32
#define LDK 40   // padded LDS row stride (elements): 80 B, keeps 16 B alignment

__device__ __forceinline__ short f2bf(float f) {
  // round-to-nearest-even fp32 -> bf16 (inputs are finite normals)
  union { float f; unsigned u; } a; a.f = f;
  unsigned r = a.u + 0x7FFFu + ((a.u >> 16) & 1u);
  return (short)(r >> 16);
}

__global__ __launch_bounds__(256) void scc_conv(
    const float* __restrict__ x, const float* __restrict__ kern,
    const float* __restrict__ bias, float* __restrict__ out)
{
  __shared__ short As[BM * LDK];   // [m][k]  k-contiguous
  __shared__ short Bs[BN * LDK];   // [f][k]  k-contiguous

  const int tid = threadIdx.x;
  const int bn  = blockIdx.x & 1;        // which 128-wide f half
  const int bm  = blockIdx.x >> 1;       // m tile
  const int m0  = bm * BM;
  const int b   = m0 >> 16;              // 256*256 positions per image
  const int h   = (m0 >> 8) & 255;
  const int w0  = m0 & 255;              // 0 or 128

  const int lane = tid & 63;
  const int wid  = tid >> 6;
  const int wm   = wid >> 1;             // wave m-half (0..1)
  const int wn   = wid & 1;              // wave n-half (0..1)
  const int fl   = lane & 15;            // fragment row/col
  const int kq   = lane >> 4;            // k-octet selector (0..3)

  // staging maps
  const int a_row0 = tid >> 3;           // 0..31 (4 iters stride 32 -> 128 rows)
  const int a_c4   = (tid & 7) * 4;      // channel quad within 32-wide slab
  const int b_f    = tid & 127;          // f row this thread stages
  const int b_kh   = tid >> 7;           // which 16-k half

  f32x4 acc[4][4];
#pragma unroll
  for (int i = 0; i < 4; ++i)
#pragma unroll
    for (int j = 0; j < 4; ++j) acc[i][j] = (f32x4){0.f, 0.f, 0.f, 0.f};

  for (int t = 0; t < 9; ++t) {
    const int dy = t / 3 - 1;
    const int dx = t % 3 - 1;
    const int hh = h + dy;
    const bool hok = ((unsigned)hh) < 256u;
    const int cbase = (t == 4) ? 128 : 0;          // center group channels
    const int gofs  = (t == 4) ? (9 * 128) : (t * 2 * 128);  // (tap*2+g)*128
    const float* __restrict__ kcol = kern + (size_t)gofs * 256 + bn * 128 + b_f;
    const float* __restrict__ xrow = x + (((size_t)b * 256 + hh) * 256) * 256;

    for (int c0 = 0; c0 < 128; c0 += BK) {
      __syncthreads();   // previous iteration's fragment reads done

      // ---- stage A: 128 rows x 32 ch, coalesced float4 channel reads ----
#pragma unroll
      for (int it = 0; it < 4; ++it) {
        const int row = a_row0 + it * 32;
        const int ww  = w0 + row + dx;
        float4 v = make_float4(0.f, 0.f, 0.f, 0.f);
        if (hok && (unsigned)ww < 256u)
          v = *(const float4*)(xrow + (size_t)ww * 256 + cbase + c0 + a_c4);
        union { short s[4]; uint2 u; } p;
        p.s[0] = f2bf(v.x); p.s[1] = f2bf(v.y);
        p.s[2] = f2bf(v.z); p.s[3] = f2bf(v.w);
        *(uint2*)&As[row * LDK + a_c4] = p.u;
      }

      // ---- stage B: 32 k x 128 f, per-thread 16 k-strided scalar reads ----
      {
        float bv[16];
#pragma unroll
        for (int i = 0; i < 16; ++i) {
          const int kk = b_kh * 16 + i;
          bv[i] = kcol[(size_t)(c0 + kk) * 256];   // lanes are f-coalesced
        }
        union { short s[16]; uint4 u[2]; } p;
#pragma unroll
        for (int i = 0; i < 16; ++i) p.s[i] = f2bf(bv[i]);
        *(uint4*)&Bs[b_f * LDK + b_kh * 16]     = p.u[0];
        *(uint4*)&Bs[b_f * LDK + b_kh * 16 + 8] = p.u[1];
      }

      __syncthreads();   // staging visible

      // ---- fragments + MFMA ----
      bf16x8 af[4], bfr[4];
#pragma unroll
      for (int i = 0; i < 4; ++i)
        af[i] = *(const bf16x8*)&As[(wm * 64 + i * 16 + fl) * LDK + kq * 8];
#pragma unroll
      for (int j = 0; j < 4; ++j)
        bfr[j] = *(const bf16x8*)&Bs[(wn * 64 + j * 16 + fl) * LDK + kq * 8];
#pragma unroll
      for (int i = 0; i < 4; ++i)
#pragma unroll
        for (int j = 0; j < 4; ++j)
          acc[i][j] = __builtin_amdgcn_mfma_f32_16x16x32_bf16(
              af[i], bfr[j], acc[i][j], 0, 0, 0);
    }
  }

  // ---- epilogue: C[row=kq*4+r][col=fl] per 16x16 tile, + bias ----
  const int of0 = bn * 128 + wn * 64;
  float bvals[4];
#pragma unroll
  for (int j = 0; j < 4; ++j) bvals[j] = bias[of0 + j * 16 + fl];

#pragma unroll
  for (int i = 0; i < 4; ++i) {
    const int mrow = m0 + wm * 64 + i * 16 + kq * 4;
#pragma unroll
    for (int j = 0; j < 4; ++j) {
      const int f = of0 + j * 16 + fl;
#pragma unroll
      for (int r = 0; r < 4; ++r)
        out[(size_t)(mrow + r) * 256 + f] = acc[i][j][r] + bvals[j];
    }
  }
}

extern "C" void kernel_launch(void* const* d_in, const int* in_sizes, int n_in,
                              void* d_out, int out_size, void* d_ws, size_t ws_size,
                              hipStream_t stream) {
  const float* x    = (const float*)d_in[0];
  const float* kern = (const float*)d_in[1];
  const float* bias = (const float*)d_in[2];
  float* out = (float*)d_out;
  // grid: 4096 m-tiles * 2 n-tiles
  scc_conv<<<dim3(8192), dim3(256), 0, stream>>>(x, kern, bias, out);
}